// Round 5
// baseline (163.337 us; speedup 1.0000x reference)
//
#include <hip/hip_runtime.h>

// ECE: ece = sum_b | sum_{i in b} (conf_i - acc_i) | / n
// Binning: xi = (int)ceilf(v*15); bin b matches xi == b+1 (consts 1..15 are
// free inline constants). v<=0 -> xi<=0 matches nothing; v>1 impossible for
// these inputs (uniform [0,1)). Bit-identical to reference jnp.ceil(c*15)-1.
//
// Scan: hand-scheduled asm. 15 v_cmp_eq_u32 into 8 rotating SGPR pairs (no
// vcc serialization), v_cndmask into 4 rotating sel temps, v_add into 15
// accumulator VGPRs. Dependency distances >= 5 instructions everywhere ->
// stall-free in-order issue; 45 VALU per element (vs ~98 compiler-emitted).

#define NB 15
#define BLOCK 256

#define SCAN15(XI, XD) \
  asm volatile( \
    "v_cmp_eq_u32 %[p0], %[xi], 1\n\t" \
    "v_cmp_eq_u32 %[p1], %[xi], 2\n\t" \
    "v_cmp_eq_u32 %[p2], %[xi], 3\n\t" \
    "v_cmp_eq_u32 %[p3], %[xi], 4\n\t" \
    "v_cmp_eq_u32 %[p4], %[xi], 5\n\t" \
    "v_cmp_eq_u32 %[p5], %[xi], 6\n\t" \
    "v_cmp_eq_u32 %[p6], %[xi], 7\n\t" \
    "v_cmp_eq_u32 %[p7], %[xi], 8\n\t" \
    "v_cndmask_b32 %[t0], 0, %[xd], %[p0]\n\t" \
    "v_cmp_eq_u32 %[p0], %[xi], 9\n\t" \
    "v_cndmask_b32 %[t1], 0, %[xd], %[p1]\n\t" \
    "v_cmp_eq_u32 %[p1], %[xi], 10\n\t" \
    "v_cndmask_b32 %[t2], 0, %[xd], %[p2]\n\t" \
    "v_cmp_eq_u32 %[p2], %[xi], 11\n\t" \
    "v_add_f32 %[a0], %[a0], %[t0]\n\t" \
    "v_cndmask_b32 %[t3], 0, %[xd], %[p3]\n\t" \
    "v_cmp_eq_u32 %[p3], %[xi], 12\n\t" \
    "v_add_f32 %[a1], %[a1], %[t1]\n\t" \
    "v_cndmask_b32 %[t0], 0, %[xd], %[p4]\n\t" \
    "v_cmp_eq_u32 %[p4], %[xi], 13\n\t" \
    "v_add_f32 %[a2], %[a2], %[t2]\n\t" \
    "v_cndmask_b32 %[t1], 0, %[xd], %[p5]\n\t" \
    "v_cmp_eq_u32 %[p5], %[xi], 14\n\t" \
    "v_add_f32 %[a3], %[a3], %[t3]\n\t" \
    "v_cndmask_b32 %[t2], 0, %[xd], %[p6]\n\t" \
    "v_cmp_eq_u32 %[p6], %[xi], 15\n\t" \
    "v_add_f32 %[a4], %[a4], %[t0]\n\t" \
    "v_cndmask_b32 %[t3], 0, %[xd], %[p7]\n\t" \
    "v_add_f32 %[a5], %[a5], %[t1]\n\t" \
    "v_cndmask_b32 %[t0], 0, %[xd], %[p0]\n\t" \
    "v_add_f32 %[a6], %[a6], %[t2]\n\t" \
    "v_cndmask_b32 %[t1], 0, %[xd], %[p1]\n\t" \
    "v_add_f32 %[a7], %[a7], %[t3]\n\t" \
    "v_cndmask_b32 %[t2], 0, %[xd], %[p2]\n\t" \
    "v_add_f32 %[a8], %[a8], %[t0]\n\t" \
    "v_cndmask_b32 %[t3], 0, %[xd], %[p3]\n\t" \
    "v_add_f32 %[a9], %[a9], %[t1]\n\t" \
    "v_cndmask_b32 %[t0], 0, %[xd], %[p4]\n\t" \
    "v_add_f32 %[a10], %[a10], %[t2]\n\t" \
    "v_cndmask_b32 %[t1], 0, %[xd], %[p5]\n\t" \
    "v_add_f32 %[a11], %[a11], %[t3]\n\t" \
    "v_cndmask_b32 %[t2], 0, %[xd], %[p6]\n\t" \
    "v_add_f32 %[a12], %[a12], %[t0]\n\t" \
    "v_add_f32 %[a13], %[a13], %[t1]\n\t" \
    "v_add_f32 %[a14], %[a14], %[t2]\n\t" \
    : [a0]"+v"(b0), [a1]"+v"(b1), [a2]"+v"(b2), [a3]"+v"(b3), \
      [a4]"+v"(b4), [a5]"+v"(b5), [a6]"+v"(b6), [a7]"+v"(b7), \
      [a8]"+v"(b8), [a9]"+v"(b9), [a10]"+v"(b10), [a11]"+v"(b11), \
      [a12]"+v"(b12), [a13]"+v"(b13), [a14]"+v"(b14), \
      [t0]"=&v"(t0), [t1]"=&v"(t1), [t2]"=&v"(t2), [t3]"=&v"(t3), \
      [p0]"=&s"(p0), [p1]"=&s"(p1), [p2]"=&s"(p2), [p3]"=&s"(p3), \
      [p4]"=&s"(p4), [p5]"=&s"(p5), [p6]"=&s"(p6), [p7]"=&s"(p7) \
    : [xi]"v"(XI), [xd]"v"(XD))

__device__ __forceinline__ unsigned ceil15(float v) {
    return (unsigned)(int)__builtin_ceilf(v * 15.0f);  // mul + ceil + cvt
}

__global__ __launch_bounds__(BLOCK, 8) void ece_hist(
        const float* __restrict__ conf,
        const float* __restrict__ acc,
        float* __restrict__ partials,   // layout [NB][nblocks]
        int n4, int n, int nblocks) {
    float b0 = 0.f, b1 = 0.f, b2 = 0.f, b3 = 0.f, b4 = 0.f;
    float b5 = 0.f, b6 = 0.f, b7 = 0.f, b8 = 0.f, b9 = 0.f;
    float b10 = 0.f, b11 = 0.f, b12 = 0.f, b13 = 0.f, b14 = 0.f;
    float t0, t1, t2, t3;
    unsigned long long p0, p1, p2, p3, p4, p5, p6, p7;

    const float4* __restrict__ c4 = (const float4*)conf;
    const float4* __restrict__ a4 = (const float4*)acc;
    const int stride = gridDim.x * blockDim.x;
    const int t = threadIdx.x;

    for (int i = blockIdx.x * blockDim.x + t; i < n4; i += stride) {
        float4 c = c4[i];
        float4 a = a4[i];
        { unsigned xi = ceil15(c.x); float d = c.x - a.x; SCAN15(xi, d); }
        { unsigned xi = ceil15(c.y); float d = c.y - a.y; SCAN15(xi, d); }
        { unsigned xi = ceil15(c.z); float d = c.z - a.z; SCAN15(xi, d); }
        { unsigned xi = ceil15(c.w); float d = c.w - a.w; SCAN15(xi, d); }
    }

    // scalar tail (n % 4) — block 0 only (n = 2^24 here, so no-op)
    if (blockIdx.x == 0) {
        for (int k = n4 * 4 + t; k < n; k += BLOCK) {
            float v = conf[k];
            unsigned xi = ceil15(v);
            float d = v - acc[k];
            SCAN15(xi, d);
        }
    }

    // wave reduction (64 lanes) over the 15 accumulators
    float bins[NB] = {b0,b1,b2,b3,b4,b5,b6,b7,b8,b9,b10,b11,b12,b13,b14};
#pragma unroll
    for (int b = 0; b < NB; ++b) {
        float v = bins[b];
#pragma unroll
        for (int off = 32; off > 0; off >>= 1)
            v += __shfl_down(v, off, 64);
        bins[b] = v;
    }

    __shared__ float wsum[4][NB];
    const int wave = t >> 6;
    const int lane = t & 63;
    if (lane == 0) {
#pragma unroll
        for (int b = 0; b < NB; ++b) wsum[wave][b] = bins[b];
    }
    __syncthreads();

    if (t < NB) {
        float s = wsum[0][t] + wsum[1][t] + wsum[2][t] + wsum[3][t];
        partials[t * nblocks + blockIdx.x] = s;   // no atomics
    }
}

__global__ __launch_bounds__(960) void ece_final(
        const float* __restrict__ partials,  // [NB][nblocks]
        float* __restrict__ out, int nblocks, float inv_n) {
    __shared__ float bsum[NB];
    const int wave = threadIdx.x >> 6;   // 15 waves, one per bin
    const int lane = threadIdx.x & 63;

    float s = 0.0f;
    for (int i = lane; i < nblocks; i += 64)
        s += partials[wave * nblocks + i];   // coalesced per wave
#pragma unroll
    for (int off = 32; off > 0; off >>= 1)
        s += __shfl_down(s, off, 64);
    if (lane == 0) bsum[wave] = s;
    __syncthreads();

    if (threadIdx.x == 0) {
        float tt = 0.0f;
#pragma unroll
        for (int b = 0; b < NB; ++b) tt += fabsf(bsum[b]);
        out[0] = tt * inv_n;
    }
}

extern "C" void kernel_launch(void* const* d_in, const int* in_sizes, int n_in,
                              void* d_out, int out_size, void* d_ws, size_t ws_size,
                              hipStream_t stream) {
    const float* conf = (const float*)d_in[0];
    const float* acc  = (const float*)d_in[1];
    float* partials   = (float*)d_ws;
    float* out        = (float*)d_out;

    const int n  = in_sizes[0];
    const int n4 = n / 4;

    int nblocks = 4096;                          // 16 blocks/CU
    while ((size_t)NB * nblocks * sizeof(float) > ws_size && nblocks > 1)
        nblocks >>= 1;
    int max_grid = (n4 + BLOCK - 1) / BLOCK;
    if (nblocks > max_grid) nblocks = max_grid;
    if (nblocks < 1) nblocks = 1;

    ece_hist<<<nblocks, BLOCK, 0, stream>>>(conf, acc, partials, n4, n, nblocks);
    ece_final<<<1, 960, 0, stream>>>(partials, out, nblocks, 1.0f / (float)n);
}